// Round 3
// baseline (58.679 us; speedup 1.0000x reference)
//
#include <hip/hip_runtime.h>
#include <math.h>

#define NPIX 65536

// ---- static device scratch (replaces d_ws; fully rewritten every call) ----
__device__ int   g_kp_idx[2048];
__device__ float g_invws[2048];
__device__ float g_nnws[2048];
__device__ float g_dws[2048 * 192];

__device__ __forceinline__ float sigmoidf_(float x) {
    return 1.0f / (1.0f + expf(-x));
}

__device__ __forceinline__ unsigned long long u64min(unsigned long long a, unsigned long long b) {
    return a < b ? a : b;
}
__device__ __forceinline__ unsigned long long u64max(unsigned long long a, unsigned long long b) {
    return a > b ? a : b;
}

// ---------------- phase 1: fused NMS + top-512 ----------------
// grid 4 (one block per image) x 1024 threads; thread t owns 8x8 window t,
// then a 1024-key bitonic sort (1 key/thread): strides<=32 via shfl_xor,
// strides 64..512 via LDS.
__global__ __launch_bounds__(1024) void nms_topk_kernel(
        const float* __restrict__ hm1, const float* __restrict__ hm2,
        float* __restrict__ out) {
    __shared__ unsigned long long keys[1024];
    int img = blockIdx.x;             // hm*2 + b
    int t = threadIdx.x;              // window id 0..1023
    int b = img & 1, hmid = img >> 1;
    const float* hp = (hmid ? hm2 : hm1) + b * NPIX;

    // --- NMS for window t: row-major scan, sigmoid compare, earliest-index tie-break
    int wy = t >> 5, wx = t & 31;
    const float* wp = hp + wy * 8 * 256 + wx * 8;
    float mv = -1.0f;
    int mi = 0;
    #pragma unroll
    for (int r = 0; r < 8; ++r) {
        float4 v0 = *reinterpret_cast<const float4*>(wp + r * 256);
        float4 v1 = *reinterpret_cast<const float4*>(wp + r * 256 + 4);
        float s[8];
        s[0] = sigmoidf_(v0.x); s[1] = sigmoidf_(v0.y);
        s[2] = sigmoidf_(v0.z); s[3] = sigmoidf_(v0.w);
        s[4] = sigmoidf_(v1.x); s[5] = sigmoidf_(v1.y);
        s[6] = sigmoidf_(v1.z); s[7] = sigmoidf_(v1.w);
        int rowbase = (wy * 8 + r) * 256 + wx * 8;
        #pragma unroll
        for (int cidx = 0; cidx < 8; ++cidx) {
            if (s[cidx] > mv) { mv = s[cidx]; mi = rowbase + cidx; }
        }
    }
    int ay = mi >> 8, ax = mi & 255;
    float val = (ay >= 10 && ay < 246 && ax >= 10 && ax < 246) ? mv : 0.0f;
    // ascending sort key: smallest key = largest val, ties -> smallest idx
    unsigned int vb = __float_as_uint(val);          // val >= 0: order-preserving bits
    unsigned long long k = ((unsigned long long)(vb ^ 0xFFFFFFFFu) << 32) |
                           (unsigned long long)(unsigned int)mi;

    // --- bitonic sort, ascending
    for (int size = 2; size <= 1024; size <<= 1) {
        for (int stride = size >> 1; stride >= 1; stride >>= 1) {
            bool dir_up = ((t & size) == 0);
            unsigned long long pk;
            if (stride >= 64) {
                __syncthreads();
                keys[t] = k;
                __syncthreads();
                pk = keys[t ^ stride];
            } else {
                pk = __shfl_xor(k, stride);
            }
            bool low = ((t & stride) == 0);
            k = ((low == dir_up)) ? u64min(k, pk) : u64max(k, pk);
        }
    }

    // --- emit rank t (t < 512)
    if (t < 512) {
        unsigned int fidx = (unsigned int)(k & 0xFFFFFFFFull);
        float v = __uint_as_float(0xFFFFFFFFu ^ (unsigned int)(k >> 32));
        int row = fidx >> 8, col = fidx & 255;
        float gx = 2.0f * (float)col / 255.0f - 1.0f;
        float gy = 2.0f * (float)row / 255.0f - 1.0f;
        // probs: keypoints sit on exact pixel centers -> bilinear == h[row,col] == v
        out[hmid * 1024 + b * 512 + t] = v;
        float* lm = out + (hmid ? 4096 : 2048) + (size_t)(b * 512 + t) * 2;
        lm[0] = gx; lm[1] = gy;
        g_kp_idx[img * 512 + t] = (int)fidx;
    }
}

// ---------------- phase 2: descriptor gather + norm precompute ----------
// grid 512 x 256 threads; one wave (64 lanes) per keypoint; lane l handles
// channels {l, l+64, l+128}. No LDS, no barriers; border mask guarantees
// x0 in [4,122] so bilinear clamps are dead.
__global__ __launch_bounds__(256) void desc_kernel(
        const float* __restrict__ f1a, const float* __restrict__ f1b,
        const float* __restrict__ f2a, const float* __restrict__ f2b) {
    int wave = threadIdx.x >> 6, lane = threadIdx.x & 63;
    int kp = blockIdx.x * 4 + wave;          // 0..2047
    int img = kp >> 9, b = img & 1, hmid = img >> 1;
    int fidx = g_kp_idx[kp];
    int row = fidx >> 8, col = fidx & 255;

    // full-res half: exact pixel -> direct gather
    const float* fa = (hmid ? f2a : f1a) + (size_t)(b * 64 + lane) * 65536;
    float vfa = fa[fidx];

    // half-res: bilinear, replicate reference arithmetic exactly
    float gx = 2.0f * (float)col / 255.0f - 1.0f;
    float gy = 2.0f * (float)row / 255.0f - 1.0f;
    float ix = (gx + 1.0f) * 0.5f * 127.0f;
    float iy = (gy + 1.0f) * 0.5f * 127.0f;
    int x0 = (int)ix, y0 = (int)iy;          // ix,iy >= 4 so trunc == floor
    float wx = ix - (float)x0, wy = iy - (float)y0;
    float w00 = (1 - wx) * (1 - wy), w01 = wx * (1 - wy);
    float w10 = (1 - wx) * wy,       w11 = wx * wy;

    const float* fb0 = (hmid ? f2b : f1b) + (size_t)(b * 128 + lane) * 16384
                       + y0 * 128 + x0;
    float vb1 = fb0[0] * w00 + fb0[1] * w01 + fb0[128] * w10 + fb0[129] * w11;
    const float* fb1 = fb0 + (size_t)64 * 16384;
    float vb2 = fb1[0] * w00 + fb1[1] * w01 + fb1[128] * w10 + fb1[129] * w11;

    float* dp = g_dws + (size_t)kp * 192;
    dp[lane]       = vfa;
    dp[lane + 64]  = vb1;
    dp[lane + 128] = vb2;

    float sq = vfa * vfa + vb1 * vb1 + vb2 * vb2;
    #pragma unroll
    for (int m = 1; m <= 32; m <<= 1) sq += __shfl_xor(sq, m);
    if (lane == 0) {
        float nrm = sqrtf(sq);
        float inv = 1.0f / (1e-6f + nrm);
        g_invws[kp] = inv;
        g_nnws[kp] = sq * inv * inv;   // ||n||^2
    }
}

// ---------------- phase 3: pairwise matching -----------------------------
// grid (8,16,2), 256 threads; 32(k1) x 64(k2) tile per block, 2x4 per thread.
__global__ __launch_bounds__(256) void match_kernel(
    const float* __restrict__ fcw, const float* __restrict__ fcb,
    float* __restrict__ out) {
    __shared__ float As[32][33];
    __shared__ float Bs[64][33];
    __shared__ float w0s[192], w1s[192];
    int b = blockIdx.z;
    int k1base = blockIdx.y * 32;
    int k2base = blockIdx.x * 64;
    int t = threadIdx.x;
    int tx = t & 15, ty = t >> 4;
    if (t < 192) { w0s[t] = fcw[t]; w1s[t] = fcw[192 + t]; }
    const float* d1 = g_dws + (size_t)(b * 512 + k1base) * 192;       // img = b
    const float* d2 = g_dws + (size_t)((2 + b) * 512 + k2base) * 192; // img = 2+b
    float dot[2][4] = {}, s0[2][4] = {}, s1[2][4] = {};
    for (int cb = 0; cb < 192; cb += 32) {
        __syncthreads();
        #pragma unroll
        for (int l = 0; l < 4; ++l) {
            int e = t + 256 * l;
            int r = e >> 5, cc = e & 31;
            As[r][cc] = d1[r * 192 + cb + cc];
        }
        #pragma unroll
        for (int l = 0; l < 8; ++l) {
            int e = t + 256 * l;
            int r = e >> 5, cc = e & 31;
            Bs[r][cc] = d2[r * 192 + cb + cc];
        }
        __syncthreads();
        #pragma unroll
        for (int cc = 0; cc < 32; ++cc) {
            float w0c = w0s[cb + cc], w1c = w1s[cb + cc];
            float a0 = As[ty][cc], a1 = As[ty + 16][cc];
            float b0 = Bs[tx][cc], b1 = Bs[tx + 16][cc];
            float b2 = Bs[tx + 32][cc], b3 = Bs[tx + 48][cc];
            float a0w0 = a0 * w0c, a1w0 = a1 * w0c;
            float a0w1 = a0 * w1c, a1w1 = a1 * w1c;
            dot[0][0] += a0 * b0; dot[0][1] += a0 * b1;
            dot[0][2] += a0 * b2; dot[0][3] += a0 * b3;
            dot[1][0] += a1 * b0; dot[1][1] += a1 * b1;
            dot[1][2] += a1 * b2; dot[1][3] += a1 * b3;
            s0[0][0] += a0w0 * b0; s0[0][1] += a0w0 * b1;
            s0[0][2] += a0w0 * b2; s0[0][3] += a0w0 * b3;
            s0[1][0] += a1w0 * b0; s0[1][1] += a1w0 * b1;
            s0[1][2] += a1w0 * b2; s0[1][3] += a1w0 * b3;
            s1[0][0] += a0w1 * b0; s1[0][1] += a0w1 * b1;
            s1[0][2] += a0w1 * b2; s1[0][3] += a0w1 * b3;
            s1[1][0] += a1w1 * b0; s1[1][1] += a1w1 * b1;
            s1[1][2] += a1w1 * b2; s1[1][3] += a1w1 * b3;
        }
    }
    float bb0 = fcb[0], bb1 = fcb[1];
    #pragma unroll
    for (int i = 0; i < 2; ++i) {
        int k1 = k1base + ty + 16 * i;
        float inv1 = g_invws[b * 512 + k1];
        float nn1  = g_nnws[b * 512 + k1];
        #pragma unroll
        for (int j = 0; j < 4; ++j) {
            int k2 = k2base + tx + 16 * j;
            float inv2 = g_invws[(2 + b) * 512 + k2];
            float nn2  = g_nnws[(2 + b) * 512 + k2];
            size_t sidx = (size_t)(b * 512 + k1) * 512 + k2;
            float2 sc = make_float2(s0[i][j] + bb0, s1[i][j] + bb1);
            *reinterpret_cast<float2*>(out + 6144 + sidx * 2) = sc;
            float arg = nn1 + nn2 - 2.0f * inv1 * inv2 * dot[i][j];
            out[1054720 + sidx] = sqrtf(fmaxf(arg, 0.0f));
        }
    }
}

extern "C" void kernel_launch(void* const* d_in, const int* in_sizes, int n_in,
                              void* d_out, int out_size, void* d_ws, size_t ws_size,
                              hipStream_t stream) {
    const float* hm1 = (const float*)d_in[0];
    const float* hm2 = (const float*)d_in[1];
    const float* f1a = (const float*)d_in[2];
    const float* f1b = (const float*)d_in[3];
    const float* f2a = (const float*)d_in[4];
    const float* f2b = (const float*)d_in[5];
    const float* fcw = (const float*)d_in[6];
    const float* fcb = (const float*)d_in[7];
    float* out = (float*)d_out;
    (void)d_ws; (void)ws_size;

    nms_topk_kernel<<<4, 1024, 0, stream>>>(hm1, hm2, out);
    desc_kernel<<<512, 256, 0, stream>>>(f1a, f1b, f2a, f2b);
    dim3 g(8, 16, 2);
    match_kernel<<<g, 256, 0, stream>>>(fcw, fcb, out);
}

// Round 4
// 39.436 us; speedup vs baseline: 1.4880x; 1.4880x over previous
//
#include <hip/hip_runtime.h>
#include <hip/hip_bf16.h>
#include <math.h>

#define NPIX 65536

typedef short short8 __attribute__((ext_vector_type(8)));
typedef float f32x4 __attribute__((ext_vector_type(4)));

// ---- static device scratch (fully rewritten every call) ----
__device__ int            g_kp_idx[2048];
__device__ float          g_invws[2048];
__device__ float          g_nnws[2048];
__device__ __hip_bfloat16 g_dbf[2048 * 192];   // all descriptors, bf16
__device__ __hip_bfloat16 g_dw0[1024 * 192];   // side-1 desc * fc_w[0,:], bf16
__device__ __hip_bfloat16 g_dw1[1024 * 192];   // side-1 desc * fc_w[1,:], bf16

__device__ __forceinline__ unsigned long long u64min(unsigned long long a, unsigned long long b) {
    return a < b ? a : b;
}
__device__ __forceinline__ unsigned long long u64max(unsigned long long a, unsigned long long b) {
    return a > b ? a : b;
}

// ---------------- phase 1: fused NMS + top-512 (logit domain) ----------------
// grid 4 (one block per image) x 1024 threads; thread t owns 8x8 window t.
// sigmoid is monotone -> argmax & sort on raw logits; sigmoid only at emit.
__global__ __launch_bounds__(1024) void nms_topk_kernel(
        const float* __restrict__ hm1, const float* __restrict__ hm2,
        float* __restrict__ out) {
    __shared__ unsigned long long keys[1024];
    int img = blockIdx.x;             // hm*2 + b
    int t = threadIdx.x;              // window id 0..1023
    int b = img & 1, hmid = img >> 1;
    const float* hp = (hmid ? hm2 : hm1) + b * NPIX;

    // --- NMS for window t: row-major scan, earliest-index tie-break
    int wy = t >> 5, wx = t & 31;
    const float* wp = hp + wy * 8 * 256 + wx * 8;
    float mv = -3.4e38f;
    int mi = 0;
    #pragma unroll
    for (int r = 0; r < 8; ++r) {
        float4 v0 = *reinterpret_cast<const float4*>(wp + r * 256);
        float4 v1 = *reinterpret_cast<const float4*>(wp + r * 256 + 4);
        float s[8] = {v0.x, v0.y, v0.z, v0.w, v1.x, v1.y, v1.z, v1.w};
        int rowbase = (wy * 8 + r) * 256 + wx * 8;
        #pragma unroll
        for (int cidx = 0; cidx < 8; ++cidx) {
            if (s[cidx] > mv) { mv = s[cidx]; mi = rowbase + cidx; }
        }
    }
    int ay = mi >> 8, ax = mi & 255;
    bool interior = (ay >= 10 && ay < 246 && ax >= 10 && ax < 246);
    // order-preserving float->uint map (ascending); masked windows -> 0
    unsigned int ub = __float_as_uint(mv);
    unsigned int mk = (ub & 0x80000000u) ? ~ub : (ub | 0x80000000u);
    if (!interior) mk = 0u;
    // ascending sort key: smallest = largest value, ties -> smallest idx
    unsigned long long k = ((unsigned long long)(~mk) << 32) |
                           (unsigned long long)(unsigned int)mi;

    // --- bitonic sort, ascending: strides<=32 via shfl, >=64 via LDS
    for (int size = 2; size <= 1024; size <<= 1) {
        for (int stride = size >> 1; stride >= 1; stride >>= 1) {
            bool dir_up = ((t & size) == 0);
            unsigned long long pk;
            if (stride >= 64) {
                __syncthreads();
                keys[t] = k;
                __syncthreads();
                pk = keys[t ^ stride];
            } else {
                pk = __shfl_xor(k, stride);
            }
            bool low = ((t & stride) == 0);
            k = ((low == dir_up)) ? u64min(k, pk) : u64max(k, pk);
        }
    }

    // --- emit rank t (t < 512)
    if (t < 512) {
        unsigned int fidx = (unsigned int)(k & 0xFFFFFFFFull);
        unsigned int mk2 = ~(unsigned int)(k >> 32);
        unsigned int lb = (mk2 & 0x80000000u) ? (mk2 ^ 0x80000000u) : ~mk2;
        float logit = __uint_as_float(lb);
        float v = 1.0f / (1.0f + expf(-logit));
        int row = fidx >> 8, col = fidx & 255;
        float gx = 2.0f * (float)col / 255.0f - 1.0f;
        float gy = 2.0f * (float)row / 255.0f - 1.0f;
        out[hmid * 1024 + b * 512 + t] = v;
        float* lm = out + (hmid ? 4096 : 2048) + (size_t)(b * 512 + t) * 2;
        lm[0] = gx; lm[1] = gy;
        g_kp_idx[img * 512 + t] = (int)fidx;
    }
}

// ---------------- phase 2: descriptor gather + norm + bf16 prep ----------
// grid 512 x 256 threads; one wave per keypoint; lane l handles channels
// {l, l+64, l+128}. Border guarantees interior bilinear (no clamps needed).
__global__ __launch_bounds__(256) void desc_kernel(
        const float* __restrict__ f1a, const float* __restrict__ f1b,
        const float* __restrict__ f2a, const float* __restrict__ f2b,
        const float* __restrict__ fcw) {
    int wave = threadIdx.x >> 6, lane = threadIdx.x & 63;
    int kp = blockIdx.x * 4 + wave;          // 0..2047
    int img = kp >> 9, b = img & 1, hmid = img >> 1;
    int fidx = g_kp_idx[kp];
    int row = fidx >> 8, col = fidx & 255;

    // full-res half: exact pixel -> direct gather
    const float* fa = (hmid ? f2a : f1a) + (size_t)(b * 64 + lane) * 65536;
    float vfa = fa[fidx];

    // half-res: bilinear, replicate reference arithmetic exactly
    float gx = 2.0f * (float)col / 255.0f - 1.0f;
    float gy = 2.0f * (float)row / 255.0f - 1.0f;
    float ix = (gx + 1.0f) * 0.5f * 127.0f;
    float iy = (gy + 1.0f) * 0.5f * 127.0f;
    int x0 = (int)ix, y0 = (int)iy;          // interior: trunc == floor
    float wx = ix - (float)x0, wy = iy - (float)y0;
    float w00 = (1 - wx) * (1 - wy), w01 = wx * (1 - wy);
    float w10 = (1 - wx) * wy,       w11 = wx * wy;

    const float* fb0 = (hmid ? f2b : f1b) + (size_t)(b * 128 + lane) * 16384
                       + y0 * 128 + x0;
    float vb1 = fb0[0] * w00 + fb0[1] * w01 + fb0[128] * w10 + fb0[129] * w11;
    const float* fb1 = fb0 + (size_t)64 * 16384;
    float vb2 = fb1[0] * w00 + fb1[1] * w01 + fb1[128] * w10 + fb1[129] * w11;

    // bf16 descriptor (for MFMA matching)
    __hip_bfloat16* dp = g_dbf + (size_t)kp * 192;
    dp[lane]       = __float2bfloat16(vfa);
    dp[lane + 64]  = __float2bfloat16(vb1);
    dp[lane + 128] = __float2bfloat16(vb2);

    // side-1 keypoints also store fc-weighted copies (fp32 product, one rounding)
    if (kp < 1024) {
        __hip_bfloat16* q0 = g_dw0 + (size_t)kp * 192;
        __hip_bfloat16* q1 = g_dw1 + (size_t)kp * 192;
        q0[lane]       = __float2bfloat16(vfa * fcw[lane]);
        q0[lane + 64]  = __float2bfloat16(vb1 * fcw[lane + 64]);
        q0[lane + 128] = __float2bfloat16(vb2 * fcw[lane + 128]);
        q1[lane]       = __float2bfloat16(vfa * fcw[192 + lane]);
        q1[lane + 64]  = __float2bfloat16(vb1 * fcw[192 + lane + 64]);
        q1[lane + 128] = __float2bfloat16(vb2 * fcw[192 + lane + 128]);
    }

    float sq = vfa * vfa + vb1 * vb1 + vb2 * vb2;
    #pragma unroll
    for (int m = 1; m <= 32; m <<= 1) sq += __shfl_xor(sq, m);
    if (lane == 0) {
        float nrm = sqrtf(sq);
        float inv = 1.0f / (1e-6f + nrm);
        g_invws[kp] = inv;
        g_nnws[kp] = sq * inv * inv;   // ||n||^2
    }
}

// ---------------- phase 3: pairwise matching via MFMA --------------------
// C = D1 * D2^T with three accumulator sets (dot, score0, score1).
// grid (8, 32, 2) x 256 thr; one wave per 16x16 output tile; no LDS.
// Fragments: A/B elem i = M[lane&15][kc + (lane>>4)*8 + i] (B^T symmetric);
// C/D: row = (lane>>4)*4 + reg, col = lane&15.
__global__ __launch_bounds__(256) void match_kernel(
        const float* __restrict__ fcb, float* __restrict__ out) {
    int t = threadIdx.x;
    int w = t >> 6, lane = t & 63;
    int b = blockIdx.z;
    int k1base = blockIdx.y * 16;
    int k2base = blockIdx.x * 64 + w * 16;
    int r1 = k1base + (lane & 15);
    int r2 = k2base + (lane & 15);
    int koff = (lane >> 4) * 8;

    const __hip_bfloat16* pA  = g_dbf + (size_t)(b * 512 + r1) * 192 + koff;
    const __hip_bfloat16* pW0 = g_dw0 + (size_t)(b * 512 + r1) * 192 + koff;
    const __hip_bfloat16* pW1 = g_dw1 + (size_t)(b * 512 + r1) * 192 + koff;
    const __hip_bfloat16* pB  = g_dbf + (size_t)((2 + b) * 512 + r2) * 192 + koff;

    f32x4 accd = {0.f, 0.f, 0.f, 0.f};
    f32x4 acc0 = {0.f, 0.f, 0.f, 0.f};
    f32x4 acc1 = {0.f, 0.f, 0.f, 0.f};
    #pragma unroll
    for (int kc = 0; kc < 6; ++kc) {
        short8 a  = *reinterpret_cast<const short8*>(pA  + kc * 32);
        short8 a0 = *reinterpret_cast<const short8*>(pW0 + kc * 32);
        short8 a1 = *reinterpret_cast<const short8*>(pW1 + kc * 32);
        short8 bb = *reinterpret_cast<const short8*>(pB  + kc * 32);
        accd = __builtin_amdgcn_mfma_f32_16x16x32_bf16(a,  bb, accd, 0, 0, 0);
        acc0 = __builtin_amdgcn_mfma_f32_16x16x32_bf16(a0, bb, acc0, 0, 0, 0);
        acc1 = __builtin_amdgcn_mfma_f32_16x16x32_bf16(a1, bb, acc1, 0, 0, 0);
    }

    float bb0 = fcb[0], bb1 = fcb[1];
    int col = lane & 15;
    int k2 = k2base + col;
    float inv2 = g_invws[(2 + b) * 512 + k2];
    float nn2  = g_nnws[(2 + b) * 512 + k2];
    #pragma unroll
    for (int j = 0; j < 4; ++j) {
        int k1 = k1base + (lane >> 4) * 4 + j;
        float inv1 = g_invws[b * 512 + k1];
        float nn1  = g_nnws[b * 512 + k1];
        size_t sidx = (size_t)(b * 512 + k1) * 512 + k2;
        float2 sc = make_float2(acc0[j] + bb0, acc1[j] + bb1);
        *reinterpret_cast<float2*>(out + 6144 + sidx * 2) = sc;
        float arg = nn1 + nn2 - 2.0f * inv1 * inv2 * accd[j];
        out[1054720 + sidx] = sqrtf(fmaxf(arg, 0.0f));
    }
}

extern "C" void kernel_launch(void* const* d_in, const int* in_sizes, int n_in,
                              void* d_out, int out_size, void* d_ws, size_t ws_size,
                              hipStream_t stream) {
    const float* hm1 = (const float*)d_in[0];
    const float* hm2 = (const float*)d_in[1];
    const float* f1a = (const float*)d_in[2];
    const float* f1b = (const float*)d_in[3];
    const float* f2a = (const float*)d_in[4];
    const float* f2b = (const float*)d_in[5];
    const float* fcw = (const float*)d_in[6];
    const float* fcb = (const float*)d_in[7];
    float* out = (float*)d_out;
    (void)d_ws; (void)ws_size;

    nms_topk_kernel<<<4, 1024, 0, stream>>>(hm1, hm2, out);
    desc_kernel<<<512, 256, 0, stream>>>(f1a, f1b, f2a, f2b, fcw);
    dim3 g(8, 32, 2);
    match_kernel<<<g, 256, 0, stream>>>(fcb, out);
}